// Round 14
// baseline (161.836 us; speedup 1.0000x reference)
//
#include <hip/hip_runtime.h>

typedef unsigned short u16;
typedef unsigned int u32;

#define NB 4
#define NN 512
#define ND 256
#define NH 256
#define TI 4

typedef __attribute__((ext_vector_type(8))) short short8;
typedef __attribute__((ext_vector_type(4))) float f32x4;

__device__ __forceinline__ u16 bfq(float f) {
    u32 t; __builtin_memcpy(&t, &f, 4);
    u32 r = (t + 0x7FFFu + ((t >> 16) & 1u)) >> 16;
    return (u16)r;
}

__device__ __forceinline__ float waveReduceSum(float v) {
#pragma unroll
    for (int o = 32; o > 0; o >>= 1) v += __shfl_down(v, o);
    return v;
}

// block-wide sum-reduce of TWO float4s (8 values) across 8 waves; 2 barriers total.
__device__ __forceinline__ void blockReduce8(float4& va, float4& vb, float4* red) {
#pragma unroll
    for (int o = 32; o > 0; o >>= 1) {
        va.x += __shfl_down(va.x, o); va.y += __shfl_down(va.y, o);
        va.z += __shfl_down(va.z, o); va.w += __shfl_down(va.w, o);
        vb.x += __shfl_down(vb.x, o); vb.y += __shfl_down(vb.y, o);
        vb.z += __shfl_down(vb.z, o); vb.w += __shfl_down(vb.w, o);
    }
    int wid = threadIdx.x >> 6;
    __syncthreads();
    if ((threadIdx.x & 63) == 0) { red[2 * wid] = va; red[2 * wid + 1] = vb; }
    __syncthreads();
    float4 ra = red[0], rb = red[1];
#pragma unroll
    for (int w = 1; w < 8; ++w) {
        float4 ua = red[2 * w], ub = red[2 * w + 1];
        ra.x += ua.x; ra.y += ua.y; ra.z += ua.z; ra.w += ua.w;
        rb.x += ub.x; rb.y += ub.y; rb.z += ub.z; rb.w += ub.w;
    }
    va = ra; vb = rb;
}

// ---------------- K0: fp32 -> bf16 convert (x, Wq, Wk, Wv, Wo) ----------------
__global__ __launch_bounds__(256) void prep_kernel(
    const float* __restrict__ x, const float* __restrict__ Wq,
    const float* __restrict__ Wk, const float* __restrict__ Wv,
    const float* __restrict__ Wo,
    u16* __restrict__ xb, u16* __restrict__ wb)
{
    const int idx4 = (blockIdx.x * 256 + threadIdx.x) * 4;   // grid covers 786432
    const float* src;
    u16* dst;
    int off;
    if (idx4 < 524288) { src = x; dst = xb; off = idx4; }
    else {
        int u = idx4 - 524288;
        int which = u >> 16; off = u & 65535;
        src = (which == 0) ? Wq : (which == 1) ? Wk : (which == 2) ? Wv : Wo;
        dst = wb + which * 65536;
    }
    float4 f = *(const float4*)(src + off);
    u32 lo = (u32)bfq(f.x) | ((u32)bfq(f.y) << 16);
    u32 hi = (u32)bfq(f.z) | ((u32)bfq(f.w) << 16);
    *(uint2*)(dst + off) = make_uint2(lo, hi);
}

// ---------------- K1: q/k/v projections, pure bf16 MFMA ----------------
// grid (32, 48). qb, kb bf16 [row][h]; v stored TRANSPOSED vt[b][h][j] bf16.
__global__ __launch_bounds__(256) void qkv_mfma(
    const u16* __restrict__ xb, const u16* __restrict__ wb,
    const float* __restrict__ bq, const float* __restrict__ bk, const float* __restrict__ bv,
    u16* __restrict__ qb, u16* __restrict__ kb, u16* __restrict__ vt)
{
    const int lane = threadIdx.x & 63, wave = threadIdx.x >> 6;
    const int r0 = blockIdx.x * 64 + wave * 16;
    const int out0 = blockIdx.y * 16;                  // 0..767
    const int which = blockIdx.y >> 4;
    const float* bia = (which == 0) ? bq : (which == 1) ? bk : bv;

    const int m = lane & 15, koff = (lane >> 4) * 8;
    const u16* Ap = xb + (size_t)(r0 + m) * 256 + koff;
    const u16* Bp = wb + which * 65536 + (size_t)((out0 & 255) + m) * 256 + koff;

    f32x4 acc = {0.f, 0.f, 0.f, 0.f};
#pragma unroll
    for (int ks = 0; ks < 8; ++ks) {
        short8 a  = *(const short8*)(Ap + ks * 32);
        short8 bb = *(const short8*)(Bp + ks * 32);
        acc = __builtin_amdgcn_mfma_f32_16x16x32_bf16(a, bb, acc, 0, 0, 0);
    }

    const int oc = (out0 + m) & 255;          // D col = lane&15
    const float bias = bia[oc];
    const int rbase = r0 + (lane >> 4) * 4;   // D row = (lane>>4)*4 + reg
#pragma unroll
    for (int reg = 0; reg < 4; ++reg) {
        int R = rbase + reg;
        u16 val = bfq(acc[reg] + bias);
        if (which == 0)      qb[(size_t)R * 256 + oc] = val;
        else if (which == 1) kb[(size_t)R * 256 + oc] = val;
        else                 vt[((size_t)(R >> 9) * 256 + oc) * 512 + (R & 511)] = val;
    }
}

// ---------------- K2: fused attention; QK, PV, Wo all on the MFMA pipe ----------------
#define PSTR 520   // srow16 row stride (u16): 512 + 8 pad
#define YSTR 264   // y16 row stride (u16): 256 + 8 pad
__global__ __launch_bounds__(512) void fused_kernel(
    const float* __restrict__ x, const float* __restrict__ area, const float* __restrict__ co,
    const float* __restrict__ We1, const float* __restrict__ be1,
    const float* __restrict__ We2, const float* __restrict__ be2,
    const u16* __restrict__ wob, const float* __restrict__ bo,
    const float* __restrict__ g_ot, const float* __restrict__ b_ot,
    const float* __restrict__ g1, const float* __restrict__ b1,
    const float* __restrict__ g2, const float* __restrict__ b2,
    const u16* __restrict__ qb, const u16* __restrict__ kb, const u16* __restrict__ vt,
    float* __restrict__ out)
{
    const int tid = threadIdx.x;
    const int b = blockIdx.x >> 7;
    const int i0 = (blockIdx.x & 127) << 2;
    const int lane = tid & 63, w = tid >> 6;

    __shared__ float histS[1024], histB[1024];
    __shared__ float pvbuf[1024];
    __shared__ float sblock[4 * 512];     // QK^T output (raw dots)
    __shared__ u16 srow16[16 * PSTR];     // P bf16, rows 4..15 zero
    __shared__ u16 y16[16 * YSTR];        // q staging, then y1 bf16; rows 4..15 zero
    __shared__ float4 red8b[16];
    __shared__ float sBaseS[4], sBaseB[4], redA[8], redB[8];

    const float be2f = be2[0];

    // ---- init: zero hist + bf16 staging buffers ----
    histS[tid] = 0.f; histS[tid + 512] = 0.f;
    histB[tid] = 0.f; histB[tid + 512] = 0.f;
    {
        u32* s32 = (u32*)srow16;                 // 4160 u32
        for (int i = tid; i < 4160; i += 512) s32[i] = 0u;
        u32* y32 = (u32*)y16;                    // 2112 u32
        for (int i = tid; i < 2112; i += 512) y32[i] = 0u;
    }
    __syncthreads();

    // ---- gate scatter + q staging (disjoint writes; both consumed after later barriers) ----
    {
        // stage q rows i0..i0+3 bf16 into y16 rows 0..3 (u32 copies)
        const u32* qsrc = (const u32*)(qb + (size_t)(b * NN + i0) * 256);
        const int ti = tid >> 7, idx = tid & 127;
        ((u32*)(y16 + ti * YSTR))[idx] = qsrc[ti * 128 + idx];

        const int s = tid >> 7, h0 = tid & 127;  // set s = w>>1 (wave-uniform)
        const float a = area[b * NN + i0 + s];
        float baS = 0.f, baB = 0.f;
#pragma unroll
        for (int k = 0; k < 2; ++k) {
            const int h = h0 + 128 * k;
            const float w10 = We1[2 * h], w11 = We1[2 * h + 1];
            const float w2v = We2[h], be1v = be1[h];
            const float al = fmaf(a, w10, be1v);
            const float sl = w11 * w2v, bb = al * w2v;
            if (w11 == 0.f) {
                if (al > 0.f) baB += bb;
            } else {
                float tt = -al / w11;
                if (w11 > 0.f) {
                    if (tt <= 0.f)      { baS += sl; baB += bb; }
                    else if (tt < 1.f) {
                        int u = (int)(tt * 256.f); u = u > 255 ? 255 : u;
                        atomicAdd(&histS[s * 256 + u], sl);
                        atomicAdd(&histB[s * 256 + u], bb);
                    }
                } else {
                    if (tt >= 1.f)      { baS += sl; baB += bb; }
                    else if (tt > 0.f) {
                        baS += sl; baB += bb;
                        int u = (int)(tt * 256.f); u = u > 255 ? 255 : u;
                        atomicAdd(&histS[s * 256 + u], -sl);
                        atomicAdd(&histB[s * 256 + u], -bb);
                    }
                }
            }
        }
        float rS = waveReduceSum(baS), rB = waveReduceSum(baB);
        if (lane == 0) { redA[w] = rS; redB[w] = rB; }
    }
    __syncthreads();
    if (tid < 4) {
        sBaseS[tid] = redA[2 * tid] + redA[2 * tid + 1];
        sBaseB[tid] = redB[2 * tid] + redB[2 * tid + 1];
    }

    // ---- in-place inclusive scan: wave s scans histS set s; wave s+4 scans histB set s ----
    {
        const int s = w & 3;
        float* hp = (w < 4) ? histS : histB;
        float b0 = hp[s * 256 + 4 * lane + 0];
        float b1 = hp[s * 256 + 4 * lane + 1];
        float b2 = hp[s * 256 + 4 * lane + 2];
        float b3 = hp[s * 256 + 4 * lane + 3];
        float p0 = b0, p1 = p0 + b1, p2 = p1 + b2, p3 = p2 + b3;
        float incl = p3;
#pragma unroll
        for (int off = 1; off < 64; off <<= 1) {
            float t = __shfl_up(incl, off);
            if (lane >= off) incl += t;
        }
        float excl = incl - p3;
        hp[s * 256 + 4 * lane + 0] = p0 + excl;
        hp[s * 256 + 4 * lane + 1] = p1 + excl;
        hp[s * 256 + 4 * lane + 2] = p2 + excl;
        hp[s * 256 + 4 * lane + 3] = p3 + excl;
    }

    // ---- QK^T via MFMA: wave w -> j-tiles {w, w+8, w+16, w+24}; A = q (y16), B = kb ----
    {
        const int m = lane & 15, koff = (lane >> 4) * 8;
        const u16* Arow = y16 + m * YSTR + koff;
        short8 afr[8];
#pragma unroll
        for (int ks = 0; ks < 8; ++ks) afr[ks] = *(const short8*)(Arow + ks * 32);
#pragma unroll
        for (int t = 0; t < 4; ++t) {
            const int j0 = (w + 8 * t) * 16;
            const u16* Bp = kb + (size_t)(b * 512 + j0 + m) * 256 + koff;
            f32x4 acc = {0.f, 0.f, 0.f, 0.f};
#pragma unroll
            for (int ks = 0; ks < 8; ++ks) {
                short8 bb = *(const short8*)(Bp + ks * 32);
                acc = __builtin_amdgcn_mfma_f32_16x16x32_bf16(afr[ks], bb, acc, 0, 0, 0);
            }
            if (lane < 16) {
#pragma unroll
                for (int reg = 0; reg < 4; ++reg)
                    sblock[reg * 512 + j0 + lane] = acc[reg];
            }
        }
    }
    __syncthreads();

    // ---- scores: gate + unnormalized exp -> P bf16 in LDS (rows 0..3) ----
    // LN1 is invariant to positive per-row scales: no max-sub, no 1/sum.
    {
#pragma unroll
        for (int ti = 0; ti < TI; ++ti) {
            float c = co[(size_t)(i0 + ti) * NN + tid];
            int u = (int)(c * 256.f); u = u > 255 ? 255 : u;
            float Sg = sBaseS[ti] + histS[ti * 256 + u];
            float Bg = sBaseB[ti] + histB[ti * 256 + u];
            float e = fmaf(c, Sg, Bg) + be2f;
            float ew = 1.f / (1.f + __expf(-e));
            srow16[ti * PSTR + tid] = bfq(__expf(sblock[ti * 512 + tid] * 0.0625f * ew));
        }
        __syncthreads();
    }

    // ---- PV via MFMA: D[i][h] = sum_j P[i][j] * vt[h][j]; wave w owns h-tiles 2w, 2w+1 ----
    {
        const int m = lane & 15, koff = (lane >> 4) * 8;
        const int t0 = 2 * w, t1 = 2 * w + 1;
        const u16* B0p = vt + ((size_t)(b * 256 + t0 * 16 + m)) * 512 + koff;
        const u16* B1p = vt + ((size_t)(b * 256 + t1 * 16 + m)) * 512 + koff;
        const u16* Arow = srow16 + m * PSTR + koff;
        f32x4 acc0 = {0.f, 0.f, 0.f, 0.f}, acc1 = {0.f, 0.f, 0.f, 0.f};
#pragma unroll
        for (int ks = 0; ks < 16; ++ks) {
            short8 a  = *(const short8*)(Arow + ks * 32);
            short8 b0 = *(const short8*)(B0p + ks * 32);
            short8 b1 = *(const short8*)(B1p + ks * 32);
            acc0 = __builtin_amdgcn_mfma_f32_16x16x32_bf16(a, b0, acc0, 0, 0, 0);
            acc1 = __builtin_amdgcn_mfma_f32_16x16x32_bf16(a, b1, acc1, 0, 0, 0);
        }
        if (lane < 16) {                 // rows 0..3 live in lanes 0..15, regs 0..3
#pragma unroll
            for (int reg = 0; reg < 4; ++reg) {
                pvbuf[reg * 256 + t0 * 16 + lane] = acc0[reg];
                pvbuf[reg * 256 + t1 * 16 + lane] = acc1[reg];
            }
        }
        __syncthreads();
    }

    // ---- LN1 (single-pass mean/var) -> y1 bf16 in LDS ----
    const int hP = tid & 255, half = tid >> 8;
    float4 sa, sb;
    float accv[TI];
#pragma unroll
    for (int ti = 0; ti < TI; ++ti) {
        accv[ti] = (half == 0) ? pvbuf[ti * 256 + hP] : 0.f;
        ((float*)&sa)[ti] = accv[ti];
        ((float*)&sb)[ti] = accv[ti] * accv[ti];
    }
    blockReduce8(sa, sb, red8b);
    if (half == 0) {
        const float g1v = g1[hP], b1v = b1[hP];
#pragma unroll
        for (int ti = 0; ti < TI; ++ti) {
            float mean = ((const float*)&sa)[ti] * (1.f / 256.f);
            float var = fmaxf(((const float*)&sb)[ti] * (1.f / 256.f) - mean * mean, 0.f);
            y16[ti * YSTR + hP] = bfq((accv[ti] - mean) * rsqrtf(var + 1e-5f) * g1v + b1v);
        }
    }
    __syncthreads();

    // ---- Wo via MFMA: D[i][o] = sum_d y1[i][d] * Wo[o][d]; wob row-major bf16 ----
    {
        const int m = lane & 15, koff = (lane >> 4) * 8;
        const int t0 = 2 * w, t1 = 2 * w + 1;
        const u16* B0p = wob + (size_t)(t0 * 16 + m) * 256 + koff;
        const u16* B1p = wob + (size_t)(t1 * 16 + m) * 256 + koff;
        const u16* Arow = y16 + m * YSTR + koff;
        f32x4 acc0 = {0.f, 0.f, 0.f, 0.f}, acc1 = {0.f, 0.f, 0.f, 0.f};
#pragma unroll
        for (int ks = 0; ks < 8; ++ks) {
            short8 a  = *(const short8*)(Arow + ks * 32);
            short8 b0 = *(const short8*)(B0p + ks * 32);
            short8 b1 = *(const short8*)(B1p + ks * 32);
            acc0 = __builtin_amdgcn_mfma_f32_16x16x32_bf16(a, b0, acc0, 0, 0, 0);
            acc1 = __builtin_amdgcn_mfma_f32_16x16x32_bf16(a, b1, acc1, 0, 0, 0);
        }
        __syncthreads();                 // pvbuf's LN1 readers done
        if (lane < 16) {
#pragma unroll
            for (int reg = 0; reg < 4; ++reg) {
                pvbuf[reg * 256 + t0 * 16 + lane] = acc0[reg];
                pvbuf[reg * 256 + t1 * 16 + lane] = acc1[reg];
            }
        }
        __syncthreads();
    }

    // ---- + bo, LN(g_ot,b_ot) + relu (single-pass) ----
    float acc2[TI];
    {
        const float bov = (half == 0) ? bo[hP] : 0.f;
#pragma unroll
        for (int ti = 0; ti < TI; ++ti) {
            acc2[ti] = (half == 0) ? pvbuf[ti * 256 + hP] + bov : 0.f;
            ((float*)&sa)[ti] = acc2[ti];
            ((float*)&sb)[ti] = acc2[ti] * acc2[ti];
        }
    }
    blockReduce8(sa, sb, red8b);
    float z[TI];
    const float gotv = (half == 0) ? g_ot[hP] : 0.f;
    const float botv = (half == 0) ? b_ot[hP] : 0.f;
#pragma unroll
    for (int ti = 0; ti < TI; ++ti) {
        float mean = ((const float*)&sa)[ti] * (1.f / 256.f);
        float var = fmaxf(((const float*)&sb)[ti] * (1.f / 256.f) - mean * mean, 0.f);
        z[ti] = fmaxf((acc2[ti] - mean) * rsqrtf(var + 1e-5f) * gotv + botv, 0.f);
    }

    // ---- residual + LN2 + store (single-pass) ----
    float tt[TI];
#pragma unroll
    for (int ti = 0; ti < TI; ++ti) {
        tt[ti] = (half == 0) ? z[ti] + x[(size_t)(b * NN + i0 + ti) * ND + hP] : 0.f;
        ((float*)&sa)[ti] = tt[ti]; ((float*)&sb)[ti] = tt[ti] * tt[ti];
    }
    blockReduce8(sa, sb, red8b);
    if (half == 0) {
        const float g2v = g2[hP], b2v = b2[hP];
#pragma unroll
        for (int ti = 0; ti < TI; ++ti) {
            float mean = ((const float*)&sa)[ti] * (1.f / 256.f);
            float var = fmaxf(((const float*)&sb)[ti] * (1.f / 256.f) - mean * mean, 0.f);
            float o = (tt[ti] - mean) * rsqrtf(var + 1e-5f) * g2v + b2v;
            out[(size_t)(b * NN + i0 + ti) * NH + hP] = o;
        }
    }
}

extern "C" void kernel_launch(void* const* d_in, const int* in_sizes, int n_in,
                              void* d_out, int out_size, void* d_ws, size_t ws_size,
                              hipStream_t stream) {
    const float* x    = (const float*)d_in[0];
    const float* area = (const float*)d_in[1];
    const float* co   = (const float*)d_in[2];
    const float* Wq   = (const float*)d_in[3];
    const float* bq   = (const float*)d_in[4];
    const float* Wk   = (const float*)d_in[5];
    const float* bk   = (const float*)d_in[6];
    const float* Wv   = (const float*)d_in[7];
    const float* bv   = (const float*)d_in[8];
    const float* We1  = (const float*)d_in[9];
    const float* be1  = (const float*)d_in[10];
    const float* We2  = (const float*)d_in[11];
    const float* be2  = (const float*)d_in[12];
    const float* Wo   = (const float*)d_in[13];
    const float* bo   = (const float*)d_in[14];
    const float* g_ot = (const float*)d_in[15];
    const float* b_ot = (const float*)d_in[16];
    const float* g1   = (const float*)d_in[17];
    const float* b1   = (const float*)d_in[18];
    const float* g2   = (const float*)d_in[19];
    const float* b2   = (const float*)d_in[20];

    u16*  xb  = (u16*)d_ws;                      // 1 MB   bf16 x [row][d]
    u16*  wb  = xb + (size_t)2048 * 256;         // 512 KB bf16 [Wq|Wk|Wv|Wo] row-major
    u16*  qb  = wb + (size_t)4 * 65536;          // 1 MB   bf16 q [row][h]
    u16*  kb  = qb + (size_t)2048 * 256;         // 1 MB   bf16 k [row][h]
    u16*  vt  = kb + (size_t)2048 * 256;         // 1 MB   bf16 v TRANSPOSED [b][h][j]

    prep_kernel<<<768, 256, 0, stream>>>(x, Wq, Wk, Wv, Wo, xb, wb);
    qkv_mfma<<<dim3(32, 48), 256, 0, stream>>>(xb, wb, bq, bk, bv, qb, kb, vt);
    fused_kernel<<<NB * NN / TI, 512, 0, stream>>>(x, area, co, We1, be1, We2, be2,
                                                   wb + 3 * 65536, bo,
                                                   g_ot, b_ot, g1, b1, g2, b2,
                                                   qb, kb, vt, (float*)d_out);
}

// Round 15
// 156.114 us; speedup vs baseline: 1.0367x; 1.0367x over previous
//
#include <hip/hip_runtime.h>

typedef unsigned short u16;
typedef unsigned int u32;

#define NB 4
#define NN 512
#define ND 256
#define NH 256
#define TI 4

typedef __attribute__((ext_vector_type(8))) short short8;
typedef __attribute__((ext_vector_type(4))) float f32x4;

__device__ __forceinline__ u16 bfq(float f) {
    u32 t; __builtin_memcpy(&t, &f, 4);
    u32 r = (t + 0x7FFFu + ((t >> 16) & 1u)) >> 16;
    return (u16)r;
}

__device__ __forceinline__ float waveReduceSum(float v) {
#pragma unroll
    for (int o = 32; o > 0; o >>= 1) v += __shfl_down(v, o);
    return v;
}

// block-wide sum-reduce of TWO float4s (8 values) across 8 waves; 2 barriers total.
__device__ __forceinline__ void blockReduce8(float4& va, float4& vb, float4* red) {
#pragma unroll
    for (int o = 32; o > 0; o >>= 1) {
        va.x += __shfl_down(va.x, o); va.y += __shfl_down(va.y, o);
        va.z += __shfl_down(va.z, o); va.w += __shfl_down(va.w, o);
        vb.x += __shfl_down(vb.x, o); vb.y += __shfl_down(vb.y, o);
        vb.z += __shfl_down(vb.z, o); vb.w += __shfl_down(vb.w, o);
    }
    int wid = threadIdx.x >> 6;
    __syncthreads();
    if ((threadIdx.x & 63) == 0) { red[2 * wid] = va; red[2 * wid + 1] = vb; }
    __syncthreads();
    float4 ra = red[0], rb = red[1];
#pragma unroll
    for (int w = 1; w < 8; ++w) {
        float4 ua = red[2 * w], ub = red[2 * w + 1];
        ra.x += ua.x; ra.y += ua.y; ra.z += ua.z; ra.w += ua.w;
        rb.x += ub.x; rb.y += ub.y; rb.z += ub.z; rb.w += ub.w;
    }
    va = ra; vb = rb;
}

// ---------------- K0: fp32 -> bf16 convert (x, Wq, Wk, Wv, Wo) ----------------
// wb layout: [which][65536], which 0..3 = Wq, Wk, Wv, Wo (row-major, no transpose).
__global__ __launch_bounds__(256) void prep_kernel(
    const float* __restrict__ x, const float* __restrict__ Wq,
    const float* __restrict__ Wk, const float* __restrict__ Wv,
    const float* __restrict__ Wo,
    u16* __restrict__ xb, u16* __restrict__ wb)
{
    const int idx4 = (blockIdx.x * 256 + threadIdx.x) * 4;   // grid covers 786432
    const float* src;
    u16* dst;
    int off;
    if (idx4 < 524288) { src = x; dst = xb; off = idx4; }
    else {
        int u = idx4 - 524288;
        int which = u >> 16; off = u & 65535;
        src = (which == 0) ? Wq : (which == 1) ? Wk : (which == 2) ? Wv : Wo;
        dst = wb + which * 65536;
    }
    float4 f = *(const float4*)(src + off);
    u32 lo = (u32)bfq(f.x) | ((u32)bfq(f.y) << 16);
    u32 hi = (u32)bfq(f.z) | ((u32)bfq(f.w) << 16);
    *(uint2*)(dst + off) = make_uint2(lo, hi);
}

// ---------------- K1: q/k/v projections, pure bf16 MFMA ----------------
// grid (32, 48). qb, kb bf16 [row][h]; v stored TRANSPOSED vt[b][h][j] bf16.
__global__ __launch_bounds__(256) void qkv_mfma(
    const u16* __restrict__ xb, const u16* __restrict__ wb,
    const float* __restrict__ bq, const float* __restrict__ bk, const float* __restrict__ bv,
    u16* __restrict__ qb, u16* __restrict__ kb, u16* __restrict__ vt)
{
    const int lane = threadIdx.x & 63, wave = threadIdx.x >> 6;
    const int r0 = blockIdx.x * 64 + wave * 16;
    const int out0 = blockIdx.y * 16;                  // 0..767
    const int which = blockIdx.y >> 4;
    const float* bia = (which == 0) ? bq : (which == 1) ? bk : bv;

    const int m = lane & 15, koff = (lane >> 4) * 8;
    const u16* Ap = xb + (size_t)(r0 + m) * 256 + koff;
    const u16* Bp = wb + which * 65536 + (size_t)((out0 & 255) + m) * 256 + koff;

    f32x4 acc = {0.f, 0.f, 0.f, 0.f};
#pragma unroll
    for (int ks = 0; ks < 8; ++ks) {
        short8 a  = *(const short8*)(Ap + ks * 32);
        short8 bb = *(const short8*)(Bp + ks * 32);
        acc = __builtin_amdgcn_mfma_f32_16x16x32_bf16(a, bb, acc, 0, 0, 0);
    }

    const int oc = (out0 + m) & 255;          // D col = lane&15
    const float bias = bia[oc];
    const int rbase = r0 + (lane >> 4) * 4;   // D row = (lane>>4)*4 + reg
#pragma unroll
    for (int reg = 0; reg < 4; ++reg) {
        int R = rbase + reg;
        u16 val = bfq(acc[reg] + bias);
        if (which == 0)      qb[(size_t)R * 256 + oc] = val;
        else if (which == 1) kb[(size_t)R * 256 + oc] = val;
        else                 vt[((size_t)(R >> 9) * 256 + oc) * 512 + (R & 511)] = val;
    }
}

// ---------------- K1b: S = Q . K^T via bf16 MFMA; wave per 16x16 tile ----------------
__global__ __launch_bounds__(256) void s_gemm(
    const u16* __restrict__ qb, const u16* __restrict__ kb, float* __restrict__ S)
{
    const int lane = threadIdx.x & 63, wave = threadIdx.x >> 6;
    const int job = blockIdx.x * 4 + wave;         // 0..4095
    const int b = job >> 10, rem = job & 1023;
    const int i0 = (rem >> 5) * 16, j0 = (rem & 31) * 16;
    const int m = lane & 15, koff = (lane >> 4) * 8;
    const u16* Ap = qb + (size_t)(b * 512 + i0 + m) * 256 + koff;
    const u16* Bp = kb + (size_t)(b * 512 + j0 + m) * 256 + koff;

    f32x4 acc = {0.f, 0.f, 0.f, 0.f};
#pragma unroll
    for (int ks = 0; ks < 8; ++ks) {
        short8 a   = *(const short8*)(Ap + ks * 32);
        short8 bb  = *(const short8*)(Bp + ks * 32);
        acc = __builtin_amdgcn_mfma_f32_16x16x32_bf16(a, bb, acc, 0, 0, 0);
    }
    const int col = j0 + m;
    const int rbase = i0 + (lane >> 4) * 4;
#pragma unroll
    for (int reg = 0; reg < 4; ++reg)
        S[(size_t)(b * 512 + rbase + reg) * 512 + col] = acc[reg];
}

// ---------------- K2: fused attention; PV and Wo on the MFMA pipe ----------------
#define PSTR 520   // srow16 row stride (u16): 512 + 8 pad -> 2-way-free LDS banks
#define YSTR 264   // y16 row stride (u16): 256 + 8 pad
__global__ __launch_bounds__(512) void fused_kernel(
    const float* __restrict__ x, const float* __restrict__ area, const float* __restrict__ co,
    const float* __restrict__ We1, const float* __restrict__ be1,
    const float* __restrict__ We2, const float* __restrict__ be2,
    const u16* __restrict__ wob, const float* __restrict__ bo,
    const float* __restrict__ g_ot, const float* __restrict__ b_ot,
    const float* __restrict__ g1, const float* __restrict__ b1,
    const float* __restrict__ g2, const float* __restrict__ b2,
    const float* __restrict__ S, const u16* __restrict__ vt,
    float* __restrict__ out)
{
    const int tid = threadIdx.x;
    const int b = blockIdx.x >> 7;
    const int i0 = (blockIdx.x & 127) << 2;
    const int lane = tid & 63, w = tid >> 6;

    __shared__ float histS[1024], histB[1024];
    __shared__ float pvbuf[1024];
    __shared__ u16 srow16[16 * PSTR];     // P bf16, rows 4..15 zero
    __shared__ u16 y16[16 * YSTR];        // y1 bf16, rows 4..15 zero
    __shared__ float4 red8b[16];
    __shared__ float sBaseS[4], sBaseB[4], redA[8], redB[8];

    const float be2f = be2[0];

    // ---- init: zero hist + bf16 staging buffers ----
    histS[tid] = 0.f; histS[tid + 512] = 0.f;
    histB[tid] = 0.f; histB[tid + 512] = 0.f;
    {
        u32* s32 = (u32*)srow16;                 // 4160 u32
        for (int i = tid; i < 4160; i += 512) s32[i] = 0u;
        u32* y32 = (u32*)y16;                    // 2112 u32
        for (int i = tid; i < 2112; i += 512) y32[i] = 0u;
    }
    __syncthreads();

    // ---- gate: scatter hinge deltas into histogram, reduce always-active bases ----
    {
        const int s = tid >> 7, h0 = tid & 127;  // set s = w>>1 (wave-uniform)
        const float a = area[b * NN + i0 + s];
        float baS = 0.f, baB = 0.f;
#pragma unroll
        for (int k = 0; k < 2; ++k) {
            const int h = h0 + 128 * k;
            const float w10 = We1[2 * h], w11 = We1[2 * h + 1];
            const float w2v = We2[h], be1v = be1[h];
            const float al = fmaf(a, w10, be1v);
            const float sl = w11 * w2v, bb = al * w2v;
            if (w11 == 0.f) {
                if (al > 0.f) baB += bb;
            } else {
                float tt = -al / w11;
                if (w11 > 0.f) {
                    if (tt <= 0.f)      { baS += sl; baB += bb; }
                    else if (tt < 1.f) {
                        int u = (int)(tt * 256.f); u = u > 255 ? 255 : u;
                        atomicAdd(&histS[s * 256 + u], sl);
                        atomicAdd(&histB[s * 256 + u], bb);
                    }
                } else {
                    if (tt >= 1.f)      { baS += sl; baB += bb; }
                    else if (tt > 0.f) {
                        baS += sl; baB += bb;
                        int u = (int)(tt * 256.f); u = u > 255 ? 255 : u;
                        atomicAdd(&histS[s * 256 + u], -sl);
                        atomicAdd(&histB[s * 256 + u], -bb);
                    }
                }
            }
        }
        float rS = waveReduceSum(baS), rB = waveReduceSum(baB);
        if (lane == 0) { redA[w] = rS; redB[w] = rB; }
    }
    __syncthreads();
    if (tid < 4) {
        sBaseS[tid] = redA[2 * tid] + redA[2 * tid + 1];
        sBaseB[tid] = redB[2 * tid] + redB[2 * tid + 1];
    }

    // ---- in-place inclusive scan: wave s scans histS set s; wave s+4 scans histB set s ----
    {
        const int s = w & 3;
        float* hp = (w < 4) ? histS : histB;
        float b0 = hp[s * 256 + 4 * lane + 0];
        float b1 = hp[s * 256 + 4 * lane + 1];
        float b2 = hp[s * 256 + 4 * lane + 2];
        float b3 = hp[s * 256 + 4 * lane + 3];
        float p0 = b0, p1 = p0 + b1, p2 = p1 + b2, p3 = p2 + b3;
        float incl = p3;
#pragma unroll
        for (int off = 1; off < 64; off <<= 1) {
            float t = __shfl_up(incl, off);
            if (lane >= off) incl += t;
        }
        float excl = incl - p3;
        hp[s * 256 + 4 * lane + 0] = p0 + excl;
        hp[s * 256 + 4 * lane + 1] = p1 + excl;
        hp[s * 256 + 4 * lane + 2] = p2 + excl;
        hp[s * 256 + 4 * lane + 3] = p3 + excl;
    }
    __syncthreads();

    // ---- scores: gate + unnormalized exp -> P bf16 in LDS (rows 0..3) ----
    // LN1 is invariant to positive per-row scales: no max-sub, no 1/sum.
    {
        const float* Sp = S + (size_t)(b * NN + i0) * 512 + tid;
#pragma unroll
        for (int ti = 0; ti < TI; ++ti) {
            float c = co[(size_t)(i0 + ti) * NN + tid];
            int u = (int)(c * 256.f); u = u > 255 ? 255 : u;
            float Sg = sBaseS[ti] + histS[ti * 256 + u];
            float Bg = sBaseB[ti] + histB[ti * 256 + u];
            float e = fmaf(c, Sg, Bg) + be2f;
            float ew = 1.f / (1.f + __expf(-e));
            srow16[ti * PSTR + tid] = bfq(__expf(Sp[(size_t)ti * 512] * 0.0625f * ew));
        }
        __syncthreads();
    }

    // ---- PV via MFMA: D[i][h] = sum_j P[i][j] * vt[h][j]; wave w owns h-tiles 2w, 2w+1 ----
    {
        const int m = lane & 15, koff = (lane >> 4) * 8;
        const int t0 = 2 * w, t1 = 2 * w + 1;
        const u16* B0p = vt + ((size_t)(b * 256 + t0 * 16 + m)) * 512 + koff;
        const u16* B1p = vt + ((size_t)(b * 256 + t1 * 16 + m)) * 512 + koff;
        const u16* Arow = srow16 + m * PSTR + koff;
        f32x4 acc0 = {0.f, 0.f, 0.f, 0.f}, acc1 = {0.f, 0.f, 0.f, 0.f};
#pragma unroll
        for (int ks = 0; ks < 16; ++ks) {
            short8 a  = *(const short8*)(Arow + ks * 32);
            short8 b0 = *(const short8*)(B0p + ks * 32);
            short8 b1 = *(const short8*)(B1p + ks * 32);
            acc0 = __builtin_amdgcn_mfma_f32_16x16x32_bf16(a, b0, acc0, 0, 0, 0);
            acc1 = __builtin_amdgcn_mfma_f32_16x16x32_bf16(a, b1, acc1, 0, 0, 0);
        }
        __syncthreads();                 // all reads of srow16 done; pvbuf free
        if (lane < 16) {                 // rows 0..3 live in lanes 0..15, regs 0..3
#pragma unroll
            for (int reg = 0; reg < 4; ++reg) {
                pvbuf[reg * 256 + t0 * 16 + lane] = acc0[reg];
                pvbuf[reg * 256 + t1 * 16 + lane] = acc1[reg];
            }
        }
        __syncthreads();
    }

    // ---- LN1 (single-pass mean/var) -> y1 bf16 in LDS ----
    const int hP = tid & 255, half = tid >> 8;
    float4 sa, sb;
    float accv[TI];
#pragma unroll
    for (int ti = 0; ti < TI; ++ti) {
        accv[ti] = (half == 0) ? pvbuf[ti * 256 + hP] : 0.f;
        ((float*)&sa)[ti] = accv[ti];
        ((float*)&sb)[ti] = accv[ti] * accv[ti];
    }
    blockReduce8(sa, sb, red8b);
    if (half == 0) {
        const float g1v = g1[hP], b1v = b1[hP];
#pragma unroll
        for (int ti = 0; ti < TI; ++ti) {
            float mean = ((const float*)&sa)[ti] * (1.f / 256.f);
            float var = fmaxf(((const float*)&sb)[ti] * (1.f / 256.f) - mean * mean, 0.f);
            y16[ti * YSTR + hP] = bfq((accv[ti] - mean) * rsqrtf(var + 1e-5f) * g1v + b1v);
        }
    }
    __syncthreads();

    // ---- Wo via MFMA: D[i][o] = sum_d y1[i][d] * Wo[o][d]; wob row-major bf16 ----
    {
        const int m = lane & 15, koff = (lane >> 4) * 8;
        const int t0 = 2 * w, t1 = 2 * w + 1;
        const u16* B0p = wob + (size_t)(t0 * 16 + m) * 256 + koff;
        const u16* B1p = wob + (size_t)(t1 * 16 + m) * 256 + koff;
        const u16* Arow = y16 + m * YSTR + koff;
        f32x4 acc0 = {0.f, 0.f, 0.f, 0.f}, acc1 = {0.f, 0.f, 0.f, 0.f};
#pragma unroll
        for (int ks = 0; ks < 8; ++ks) {
            short8 a  = *(const short8*)(Arow + ks * 32);
            short8 b0 = *(const short8*)(B0p + ks * 32);
            short8 b1 = *(const short8*)(B1p + ks * 32);
            acc0 = __builtin_amdgcn_mfma_f32_16x16x32_bf16(a, b0, acc0, 0, 0, 0);
            acc1 = __builtin_amdgcn_mfma_f32_16x16x32_bf16(a, b1, acc1, 0, 0, 0);
        }
        __syncthreads();                 // pvbuf's previous readers done
        if (lane < 16) {
#pragma unroll
            for (int reg = 0; reg < 4; ++reg) {
                pvbuf[reg * 256 + t0 * 16 + lane] = acc0[reg];
                pvbuf[reg * 256 + t1 * 16 + lane] = acc1[reg];
            }
        }
        __syncthreads();
    }

    // ---- + bo, LN(g_ot,b_ot) + relu (single-pass) ----
    float acc2[TI];
    {
        const float bov = (half == 0) ? bo[hP] : 0.f;
#pragma unroll
        for (int ti = 0; ti < TI; ++ti) {
            acc2[ti] = (half == 0) ? pvbuf[ti * 256 + hP] + bov : 0.f;
            ((float*)&sa)[ti] = acc2[ti];
            ((float*)&sb)[ti] = acc2[ti] * acc2[ti];
        }
    }
    blockReduce8(sa, sb, red8b);
    float z[TI];
    const float gotv = (half == 0) ? g_ot[hP] : 0.f;
    const float botv = (half == 0) ? b_ot[hP] : 0.f;
#pragma unroll
    for (int ti = 0; ti < TI; ++ti) {
        float mean = ((const float*)&sa)[ti] * (1.f / 256.f);
        float var = fmaxf(((const float*)&sb)[ti] * (1.f / 256.f) - mean * mean, 0.f);
        z[ti] = fmaxf((acc2[ti] - mean) * rsqrtf(var + 1e-5f) * gotv + botv, 0.f);
    }

    // ---- residual + LN2 + store (single-pass) ----
    float tt[TI];
#pragma unroll
    for (int ti = 0; ti < TI; ++ti) {
        tt[ti] = (half == 0) ? z[ti] + x[(size_t)(b * NN + i0 + ti) * ND + hP] : 0.f;
        ((float*)&sa)[ti] = tt[ti]; ((float*)&sb)[ti] = tt[ti] * tt[ti];
    }
    blockReduce8(sa, sb, red8b);
    if (half == 0) {
        const float g2v = g2[hP], b2v = b2[hP];
#pragma unroll
        for (int ti = 0; ti < TI; ++ti) {
            float mean = ((const float*)&sa)[ti] * (1.f / 256.f);
            float var = fmaxf(((const float*)&sb)[ti] * (1.f / 256.f) - mean * mean, 0.f);
            float o = (tt[ti] - mean) * rsqrtf(var + 1e-5f) * g2v + b2v;
            out[(size_t)(b * NN + i0 + ti) * NH + hP] = o;
        }
    }
}

extern "C" void kernel_launch(void* const* d_in, const int* in_sizes, int n_in,
                              void* d_out, int out_size, void* d_ws, size_t ws_size,
                              hipStream_t stream) {
    const float* x    = (const float*)d_in[0];
    const float* area = (const float*)d_in[1];
    const float* co   = (const float*)d_in[2];
    const float* Wq   = (const float*)d_in[3];
    const float* bq   = (const float*)d_in[4];
    const float* Wk   = (const float*)d_in[5];
    const float* bk   = (const float*)d_in[6];
    const float* Wv   = (const float*)d_in[7];
    const float* bv   = (const float*)d_in[8];
    const float* We1  = (const float*)d_in[9];
    const float* be1  = (const float*)d_in[10];
    const float* We2  = (const float*)d_in[11];
    const float* be2  = (const float*)d_in[12];
    const float* Wo   = (const float*)d_in[13];
    const float* bo   = (const float*)d_in[14];
    const float* g_ot = (const float*)d_in[15];
    const float* b_ot = (const float*)d_in[16];
    const float* g1   = (const float*)d_in[17];
    const float* b1   = (const float*)d_in[18];
    const float* g2   = (const float*)d_in[19];
    const float* b2   = (const float*)d_in[20];

    u16*  xb  = (u16*)d_ws;                      // 1 MB   bf16 x [row][d]
    u16*  wb  = xb + (size_t)2048 * 256;         // 512 KB bf16 [Wq|Wk|Wv|Wo] row-major
    u16*  qb  = wb + (size_t)4 * 65536;          // 1 MB   bf16 q [row][h]
    u16*  kb  = qb + (size_t)2048 * 256;         // 1 MB   bf16 k [row][h]
    u16*  vt  = kb + (size_t)2048 * 256;         // 1 MB   bf16 v TRANSPOSED [b][h][j]
    float* S  = (float*)(vt + (size_t)2048 * 256);  // 4 MB fp32 scores

    prep_kernel<<<768, 256, 0, stream>>>(x, Wq, Wk, Wv, Wo, xb, wb);
    qkv_mfma<<<dim3(32, 48), 256, 0, stream>>>(xb, wb, bq, bk, bv, qb, kb, vt);
    s_gemm<<<1024, 256, 0, stream>>>(qb, kb, S);
    fused_kernel<<<NB * NN / TI, 512, 0, stream>>>(x, area, co, We1, be1, We2, be2,
                                                   wb + 3 * 65536, bo,
                                                   g_ot, b_ot, g1, b1, g2, b2,
                                                   S, vt, (float*)d_out);
}